// Round 5
// baseline (235.254 us; speedup 1.0000x reference)
//
#include <hip/hip_runtime.h>
#include <math.h>

#define DFEAT   128
#define KSPLIT  16      // blocks per segment
#define NEG_INF (-INFINITY)
#define SCALE   0.08838834764831845f   // 1/sqrt(128)

typedef float f32x4 __attribute__((ext_vector_type(4)));  // native vec for nontemporal builtin

// sum across the 16-lane group using DPP only (no DS pipe):
// xor1 (quad_perm [1,0,3,2]), xor2 (quad_perm [2,3,0,1]),
// row_half_mirror, row_mirror.
__device__ __forceinline__ float red16(float s) {
    s += __int_as_float(__builtin_amdgcn_update_dpp(0, __float_as_int(s), 0xB1,  0xF, 0xF, true));
    s += __int_as_float(__builtin_amdgcn_update_dpp(0, __float_as_int(s), 0x4E,  0xF, 0xF, true));
    s += __int_as_float(__builtin_amdgcn_update_dpp(0, __float_as_int(s), 0x141, 0xF, 0xF, true));
    s += __int_as_float(__builtin_amdgcn_update_dpp(0, __float_as_int(s), 0x140, 0xF, 0xF, true));
    return s;
}

__device__ __forceinline__ float dot8(const float4& xa, const float4& xb,
                                      const float4& qa, const float4& qb) {
    return xa.x*qa.x + xa.y*qa.y + xa.z*qa.z + xa.w*qa.w
         + xb.x*qb.x + xb.y*qb.y + xb.z*qb.z + xb.w*qb.w;
}

// ---------------------------------------------------------------------------
// Fused: each of B*KSPLIT blocks streams slice j of segment seg (online
// softmax partial) AND writes its share of the zero-fill of H rows [B, V).
// 256 threads = 16 groups of 16 lanes.
// Lane ln owns cols [4ln,4ln+4) and [64+4ln,64+4ln+4)  ->  every load
// instruction is lane-contiguous (16 x 16B = 256B fully-used lines).
// ---------------------------------------------------------------------------
__global__ __launch_bounds__(256) void fused_kernel(
    const float* __restrict__ node_feats,
    const float* __restrict__ Q,
    const int*   __restrict__ bidx,
    int V, int B,
    float* __restrict__ H,
    float* __restrict__ M, float* __restrict__ Zp, float* __restrict__ NUM)
{
    const int blk = blockIdx.x;
    const int seg = blk / KSPLIT;
    const int j   = blk % KSPLIT;
    const int tid = threadIdx.x;
    const int grp = tid >> 4;
    const int ln  = tid & 15;

    // ---- zero-fill bookkeeping (rows [B, V)) ----
    f32x4* fdst = (f32x4*)(H + (size_t)B * DFEAT);
    const size_t ftot = ((size_t)(V - B) * DFEAT) >> 2;   // float4 count
    const size_t fstr = (size_t)gridDim.x * 256;
    size_t kf = (size_t)blk * 256 + tid;
    const f32x4 z4 = {0.f, 0.f, 0.f, 0.f};

    // ---- segment bounds: inline lower_bound (uniform across block) ----
    int lo = 0, hi = V;
    while (lo < hi) { int mid = (lo + hi) >> 1; if (bidx[mid] < seg) lo = mid + 1; else hi = mid; }
    const int start = lo;
    hi = V;
    while (lo < hi) { int mid = (lo + hi) >> 1; if (bidx[mid] < seg + 1) lo = mid + 1; else hi = mid; }
    const int end = lo;

    const int len  = end - start;
    const int my_s = start + (int)(((long long)len * j)       / KSPLIT);
    const int my_e = start + (int)(((long long)len * (j + 1)) / KSPLIT);

    const float4* nf = (const float4*)node_feats;
    const float4* qr = (const float4*)(Q + (size_t)seg * DFEAT);
    const float4 qa = qr[ln];        // cols 4ln..4ln+3
    const float4 qb = qr[16 + ln];   // cols 64+4ln..64+4ln+3

    float m = NEG_INF, Z = 0.f;
    float num[8] = {0.f, 0.f, 0.f, 0.f, 0.f, 0.f, 0.f, 0.f};

    int v = my_s + grp;
    // ---- main loop: 4 nodes per group-iteration, 8 loads in flight ----
    for (; v + 48 < my_e; v += 64) {
        const float4* p0 = nf + (size_t)v        * 32 + ln;
        const float4* p1 = nf + (size_t)(v + 16) * 32 + ln;
        const float4* p2 = nf + (size_t)(v + 32) * 32 + ln;
        const float4* p3 = nf + (size_t)(v + 48) * 32 + ln;
        const float4 xa0 = p0[0], xb0 = p0[16];
        const float4 xa1 = p1[0], xb1 = p1[16];
        const float4 xa2 = p2[0], xb2 = p2[16];
        const float4 xa3 = p3[0], xb3 = p3[16];

        // interleaved zero-fill stores (independent of the loads), 1:1 bytes
        #pragma unroll
        for (int t = 0; t < 8; ++t) {
            if (kf < ftot) __builtin_nontemporal_store(z4, &fdst[kf]);
            kf += fstr;
        }

        float s0 = red16(dot8(xa0, xb0, qa, qb)) * SCALE;
        float s1 = red16(dot8(xa1, xb1, qa, qb)) * SCALE;
        float s2 = red16(dot8(xa2, xb2, qa, qb)) * SCALE;
        float s3 = red16(dot8(xa3, xb3, qa, qb)) * SCALE;

        const float mn = fmaxf(fmaxf(fmaxf(s0, s1), fmaxf(s2, s3)), m);
        const float f  = __expf(m  - mn);   // 1 if no new max; 0 on first
        const float e0 = __expf(s0 - mn);
        const float e1 = __expf(s1 - mn);
        const float e2 = __expf(s2 - mn);
        const float e3 = __expf(s3 - mn);
        Z = Z * f + e0 + e1 + e2 + e3;
        num[0] = num[0]*f + e0*xa0.x + e1*xa1.x + e2*xa2.x + e3*xa3.x;
        num[1] = num[1]*f + e0*xa0.y + e1*xa1.y + e2*xa2.y + e3*xa3.y;
        num[2] = num[2]*f + e0*xa0.z + e1*xa1.z + e2*xa2.z + e3*xa3.z;
        num[3] = num[3]*f + e0*xa0.w + e1*xa1.w + e2*xa2.w + e3*xa3.w;
        num[4] = num[4]*f + e0*xb0.x + e1*xb1.x + e2*xb2.x + e3*xb3.x;
        num[5] = num[5]*f + e0*xb0.y + e1*xb1.y + e2*xb2.y + e3*xb3.y;
        num[6] = num[6]*f + e0*xb0.z + e1*xb1.z + e2*xb2.z + e3*xb3.z;
        num[7] = num[7]*f + e0*xb0.w + e1*xb1.w + e2*xb2.w + e3*xb3.w;
        m = mn;
    }
    // ---- tail: one node at a time ----
    for (; v < my_e; v += 16) {
        const float4* p0 = nf + (size_t)v * 32 + ln;
        const float4 xa = p0[0], xb = p0[16];
        const float s  = red16(dot8(xa, xb, qa, qb)) * SCALE;
        const float mn = fmaxf(s, m);
        const float f  = __expf(m - mn);
        const float e  = __expf(s - mn);
        Z = Z * f + e;
        num[0] = num[0]*f + e*xa.x;  num[1] = num[1]*f + e*xa.y;
        num[2] = num[2]*f + e*xa.z;  num[3] = num[3]*f + e*xa.w;
        num[4] = num[4]*f + e*xb.x;  num[5] = num[5]*f + e*xb.y;
        num[6] = num[6]*f + e*xb.z;  num[7] = num[7]*f + e*xb.w;
        m = mn;
    }
    // drain remaining zero-fill quota
    for (; kf < ftot; kf += fstr) __builtin_nontemporal_store(z4, &fdst[kf]);

    // ---- merge 16 group-partials (m, Z uniform within each group) ----
    __shared__ float gm[16], gz[16];
    __shared__ float nm[16][DFEAT];
    if (ln == 0) { gm[grp] = m; gz[grp] = Z; }
    __syncthreads();

    float mstar = gm[0];
    #pragma unroll
    for (int k = 1; k < 16; ++k) mstar = fmaxf(mstar, gm[k]);

    const float fs = (m == NEG_INF) ? 0.f : __expf(m - mstar);
    #pragma unroll
    for (int i = 0; i < 4; ++i) {
        nm[grp][4 * ln + i]      = num[i]     * fs;   // cols 4ln..
        nm[grp][64 + 4 * ln + i] = num[4 + i] * fs;   // cols 64+4ln..
    }
    __syncthreads();

    if (tid < DFEAT) {
        float acc = 0.f;
        #pragma unroll
        for (int k = 0; k < 16; ++k) acc += nm[k][tid];
        NUM[(size_t)blk * DFEAT + tid] = acc;
    }
    if (tid == 0) {
        float Zb = 0.f;
        #pragma unroll
        for (int k = 0; k < 16; ++k) {
            const float fk = (gm[k] == NEG_INF) ? 0.f : __expf(gm[k] - mstar);
            Zb += gz[k] * fk;
        }
        M[blk]  = mstar;   // -inf if slice empty
        Zp[blk] = Zb;
    }
}

// ---------------------------------------------------------------------------
// pass2: merge the KSPLIT partials of each segment, write H rows [0, B).
// ---------------------------------------------------------------------------
__global__ __launch_bounds__(128) void pass2_kernel(
    const float* __restrict__ M, const float* __restrict__ Zp,
    const float* __restrict__ NUM, float* __restrict__ H)
{
    const int b = blockIdx.x;
    const int d = threadIdx.x;

    float mstar = NEG_INF;
    #pragma unroll
    for (int i = 0; i < KSPLIT; ++i) mstar = fmaxf(mstar, M[b * KSPLIT + i]);

    if (mstar == NEG_INF) {          // empty segment -> zero row
        H[(size_t)b * DFEAT + d] = 0.f;
        return;
    }

    float W = 0.f, acc = 0.f;
    #pragma unroll
    for (int i = 0; i < KSPLIT; ++i) {
        const float mi = M[b * KSPLIT + i];
        const float fi = (mi == NEG_INF) ? 0.f : __expf(mi - mstar);
        W   += Zp[b * KSPLIT + i] * fi;
        acc += NUM[(size_t)(b * KSPLIT + i) * DFEAT + d] * fi;
    }
    H[(size_t)b * DFEAT + d] = acc / W;   // W >= 1 when segment nonempty
}

// ---------------------------------------------------------------------------
extern "C" void kernel_launch(void* const* d_in, const int* in_sizes, int n_in,
                              void* d_out, int out_size, void* d_ws, size_t ws_size,
                              hipStream_t stream) {
    const float* node_feats = (const float*)d_in[0];  // [V, 128]
    const float* Q          = (const float*)d_in[1];  // [B, 128]
    const int*   bidx       = (const int*)  d_in[2];  // [V] sorted
    float*       H          = (float*)d_out;          // [V, 128]

    const int V = in_sizes[2];
    const int B = in_sizes[1] / DFEAT;

    // workspace layout (512B-aligned chunks)
    char* ws = (char*)d_ws;
    size_t off = 0;
    float* M  = (float*)(ws + off);
    off += ((size_t)B * KSPLIT * sizeof(float) + 511) & ~(size_t)511;
    float* Zp = (float*)(ws + off);
    off += ((size_t)B * KSPLIT * sizeof(float) + 511) & ~(size_t)511;
    float* NUM = (float*)(ws + off);

    fused_kernel<<<B * KSPLIT, 256, 0, stream>>>(
        node_feats, Q, bidx, V, B, H, M, Zp, NUM);
    pass2_kernel<<<B, DFEAT, 0, stream>>>(M, Zp, NUM, H);
}

// Round 6
// 228.426 us; speedup vs baseline: 1.0299x; 1.0299x over previous
//
#include <hip/hip_runtime.h>
#include <math.h>

#define DFEAT   128
#define KSPLIT  16      // blocks per segment
#define NEG_INF (-INFINITY)
#define SCALE   0.08838834764831845f   // 1/sqrt(128)

typedef float f32x4 __attribute__((ext_vector_type(4)));  // native vec for nontemporal builtin

// sum across the 16-lane group using DPP only (no DS pipe):
// xor1 (quad_perm [1,0,3,2]), xor2 (quad_perm [2,3,0,1]),
// row_half_mirror, row_mirror.
__device__ __forceinline__ float red16(float s) {
    s += __int_as_float(__builtin_amdgcn_update_dpp(0, __float_as_int(s), 0xB1,  0xF, 0xF, true));
    s += __int_as_float(__builtin_amdgcn_update_dpp(0, __float_as_int(s), 0x4E,  0xF, 0xF, true));
    s += __int_as_float(__builtin_amdgcn_update_dpp(0, __float_as_int(s), 0x141, 0xF, 0xF, true));
    s += __int_as_float(__builtin_amdgcn_update_dpp(0, __float_as_int(s), 0x140, 0xF, 0xF, true));
    return s;
}

// ---------------------------------------------------------------------------
// Fused: each of B*KSPLIT blocks streams slice j of segment seg (deferred-base
// online softmax partial) AND writes its share of the zero-fill of H rows
// [B, V) with interleaved nontemporal stores.
// 256 threads = 16 groups of 16 lanes; lane ln owns cols [4ln,4ln+4) and
// [64+4ln,64+4ln+4) -> every load instruction is lane-contiguous (256B).
// Register pipeline: depth-3 (A/B/C), 1 node per group-iteration.
// VGPR target <= 64 for 8 waves/SIMD.
// ---------------------------------------------------------------------------
__global__ __launch_bounds__(256) void fused_kernel(
    const float* __restrict__ node_feats,
    const float* __restrict__ Q,
    const int*   __restrict__ bidx,
    int V, int B,
    float* __restrict__ H,
    float* __restrict__ M, float* __restrict__ Zp, float* __restrict__ NUM)
{
    const int blk = blockIdx.x;
    const int seg = blk >> 4;          // / KSPLIT
    const int j   = blk & (KSPLIT - 1);
    const int tid = threadIdx.x;
    const int grp = tid >> 4;
    const int ln  = tid & 15;

    // ---- zero-fill bookkeeping (rows [B, V)) ----
    f32x4* fdst = (f32x4*)(H + (size_t)B * DFEAT);
    const size_t ftot = ((size_t)(V - B) * DFEAT) >> 2;   // float4 count
    const size_t fstr = (size_t)gridDim.x * 256;
    size_t kf = (size_t)blk * 256 + tid;
    const f32x4 z4 = {0.f, 0.f, 0.f, 0.f};

    // ---- segment bounds: inline lower_bound (uniform across block) ----
    int lo = 0, hi = V;
    while (lo < hi) { int mid = (lo + hi) >> 1; if (bidx[mid] < seg) lo = mid + 1; else hi = mid; }
    const int start = lo;
    hi = V;
    while (lo < hi) { int mid = (lo + hi) >> 1; if (bidx[mid] < seg + 1) lo = mid + 1; else hi = mid; }
    const int end = lo;

    const int len  = end - start;
    const int my_s = start + (int)(((long long)len * j)       / KSPLIT);
    const int my_e = start + (int)(((long long)len * (j + 1)) / KSPLIT);

    // per-group exact trip count: nodes v = my_s+grp+16k, k in [0,T)
    const int rem = my_e - (my_s + grp);
    const int T   = rem > 0 ? ((rem + 15) >> 4) : 0;

    const char* nfc = (const char*)node_feats;
    const uint  base_off = (((uint)(my_s + grp)) << 9) + (((uint)ln) << 4);

    const float4* qr = (const float4*)(Q + (size_t)seg * DFEAT);
    const float4 qa = qr[ln];        // cols 4ln..4ln+3
    const float4 qb = qr[16 + ln];   // cols 64+4ln..64+4ln+3

    float base = 0.f, Z = 0.f;       // deferred-base online softmax
    float num[8] = {0.f, 0.f, 0.f, 0.f, 0.f, 0.f, 0.f, 0.f};

    float4 A0, A1, B0, B1, C0, C1;

#define ISSUE(X0, X1, kk) do {                                              \
        if ((kk) < T) {                                                     \
            const uint o = base_off + (((uint)(kk)) << 13);                 \
            X0 = *(const float4*)(nfc + o);                                 \
            X1 = *(const float4*)(nfc + o + 256);                           \
        }                                                                   \
    } while (0)

#define FILL2() do {                                                        \
        if (kf < ftot) __builtin_nontemporal_store(z4, &fdst[kf]);          \
        kf += fstr;                                                         \
        if (kf < ftot) __builtin_nontemporal_store(z4, &fdst[kf]);          \
        kf += fstr;                                                         \
    } while (0)

#define COMPUTE(X0, X1) do {                                                \
        float s = X0.x*qa.x + X0.y*qa.y + X0.z*qa.z + X0.w*qa.w             \
                + X1.x*qb.x + X1.y*qb.y + X1.z*qb.z + X1.w*qb.w;            \
        s = red16(s) * SCALE;                                               \
        if (__builtin_expect(s > base + 8.f, 0)) {                          \
            const float rf = __expf(base - s);                              \
            Z *= rf;                                                        \
            num[0]*=rf; num[1]*=rf; num[2]*=rf; num[3]*=rf;                 \
            num[4]*=rf; num[5]*=rf; num[6]*=rf; num[7]*=rf;                 \
            base = s;                                                       \
        }                                                                   \
        const float e = __expf(s - base);                                   \
        Z += e;                                                             \
        num[0] += e*X0.x; num[1] += e*X0.y; num[2] += e*X0.z; num[3] += e*X0.w; \
        num[4] += e*X1.x; num[5] += e*X1.y; num[6] += e*X1.z; num[7] += e*X1.w; \
    } while (0)

    ISSUE(A0, A1, 0);
    ISSUE(B0, B1, 1);
    ISSUE(C0, C1, 2);

    int k = 0;
    while (k < T) {
        COMPUTE(A0, A1); FILL2(); ISSUE(A0, A1, k + 3); ++k;
        if (k >= T) break;
        COMPUTE(B0, B1); FILL2(); ISSUE(B0, B1, k + 3); ++k;
        if (k >= T) break;
        COMPUTE(C0, C1); FILL2(); ISSUE(C0, C1, k + 3); ++k;
    }
    // drain remaining zero-fill quota
    for (; kf < ftot; kf += fstr) __builtin_nontemporal_store(z4, &fdst[kf]);

#undef ISSUE
#undef FILL2
#undef COMPUTE

    // ---- merge 16 group-partials (base, Z uniform within each group) ----
    __shared__ float gm[16], gz[16];
    __shared__ float nm[16][DFEAT];
    if (ln == 0) { gm[grp] = base; gz[grp] = Z; }
    __syncthreads();

    float mstar = gm[0];
    #pragma unroll
    for (int t = 1; t < 16; ++t) mstar = fmaxf(mstar, gm[t]);

    const float fs = __expf(base - mstar);   // empty group: Z=0, num=0 -> harmless
    #pragma unroll
    for (int i = 0; i < 4; ++i) {
        nm[grp][4 * ln + i]      = num[i]     * fs;   // cols 4ln..
        nm[grp][64 + 4 * ln + i] = num[4 + i] * fs;   // cols 64+4ln..
    }
    __syncthreads();

    if (tid < DFEAT) {
        float acc = 0.f;
        #pragma unroll
        for (int t = 0; t < 16; ++t) acc += nm[t][tid];
        NUM[(size_t)blk * DFEAT + tid] = acc;
    }
    if (tid == 0) {
        float Zb = 0.f;
        #pragma unroll
        for (int t = 0; t < 16; ++t) Zb += gz[t] * __expf(gm[t] - mstar);
        M[blk]  = mstar;
        Zp[blk] = Zb;   // 0 if slice empty
    }
}

// ---------------------------------------------------------------------------
// pass2: merge the KSPLIT partials of each segment, write H rows [0, B).
// ---------------------------------------------------------------------------
__global__ __launch_bounds__(128) void pass2_kernel(
    const float* __restrict__ M, const float* __restrict__ Zp,
    const float* __restrict__ NUM, float* __restrict__ H)
{
    const int b = blockIdx.x;
    const int d = threadIdx.x;

    float mstar = NEG_INF;
    #pragma unroll
    for (int i = 0; i < KSPLIT; ++i) mstar = fmaxf(mstar, M[b * KSPLIT + i]);

    float W = 0.f, acc = 0.f;
    #pragma unroll
    for (int i = 0; i < KSPLIT; ++i) {
        const float fi = __expf(M[b * KSPLIT + i] - mstar);
        W   += Zp[b * KSPLIT + i] * fi;
        acc += NUM[(size_t)(b * KSPLIT + i) * DFEAT + d] * fi;
    }
    // W == 0 only for a fully-empty segment -> reference row is 0
    H[(size_t)b * DFEAT + d] = (W > 0.f) ? (acc / W) : 0.f;
}

// ---------------------------------------------------------------------------
extern "C" void kernel_launch(void* const* d_in, const int* in_sizes, int n_in,
                              void* d_out, int out_size, void* d_ws, size_t ws_size,
                              hipStream_t stream) {
    const float* node_feats = (const float*)d_in[0];  // [V, 128]
    const float* Q          = (const float*)d_in[1];  // [B, 128]
    const int*   bidx       = (const int*)  d_in[2];  // [V] sorted
    float*       H          = (float*)d_out;          // [V, 128]

    const int V = in_sizes[2];
    const int B = in_sizes[1] / DFEAT;

    // workspace layout (512B-aligned chunks)
    char* ws = (char*)d_ws;
    size_t off = 0;
    float* M  = (float*)(ws + off);
    off += ((size_t)B * KSPLIT * sizeof(float) + 511) & ~(size_t)511;
    float* Zp = (float*)(ws + off);
    off += ((size_t)B * KSPLIT * sizeof(float) + 511) & ~(size_t)511;
    float* NUM = (float*)(ws + off);

    fused_kernel<<<B * KSPLIT, 256, 0, stream>>>(
        node_feats, Q, bidx, V, B, H, M, Zp, NUM);
    pass2_kernel<<<B, DFEAT, 0, stream>>>(M, Zp, NUM, H);
}